// Round 3
// baseline (301.802 us; speedup 1.0000x reference)
//
#include <hip/hip_runtime.h>
#include <cstddef>

#define NB 64
#define NQ 64
#define NK 8192
#define ND 64

// ---------------------------------------------------------------------------
// Kernel 1: per (b, 128-key tile). 256 threads = 4 waves.
// Thread (kA = tid&63, qg = tid>>6) owns key columns kA, kA+64 and q-range
// [16*qg, 16*qg+16): 2x16 = 32 accumulators (fits VGPRs; round-1's 2x64
// layout was runtime-indexed -> scratch, VGPR=80 + 180MB spill traffic).
// Per-column softmax over ALL 64 q = local 16-q reduce + 4-way cross-wave
// reduce through small LDS buffers.
// ---------------------------------------------------------------------------
#define KPB 128
__global__ __launch_bounds__(256, 2) void k_qk_softmax(
    const float* __restrict__ query,
    const float* __restrict__ key,
    float* __restrict__ attn,
    float* __restrict__ rowsum)
{
    __shared__ alignas(16) float Qs[NQ * ND];     // 16 KB; reads are broadcast
    __shared__ alignas(16) float Ks[KPB * 68];    // +4 pad: k-strided b128 reads
    __shared__ float Mloc[4][KPB];
    __shared__ float Sloc[4][KPB];

    const int b   = blockIdx.y;
    const int tid = threadIdx.x;
    const int k0  = blockIdx.x * KPB;

    // stage Q[b] (1024 float4, coalesced)
    {
        const float4* qg4 = reinterpret_cast<const float4*>(query + (size_t)b * NQ * ND);
        float4* qs = reinterpret_cast<float4*>(Qs);
#pragma unroll
        for (int i = 0; i < 4; ++i) qs[tid + 256 * i] = qg4[tid + 256 * i];
    }
    // stage K tile (2048 float4, coalesced; padded rows in LDS)
    {
        const float4* kg = reinterpret_cast<const float4*>(key + ((size_t)b * NK + k0) * ND);
#pragma unroll
        for (int i = 0; i < 8; ++i) {
            const int idx = tid + 256 * i;          // 0..2047
            const int row = idx >> 4, c4 = (idx & 15) * 4;
            *reinterpret_cast<float4*>(&Ks[row * 68 + c4]) = kg[idx];
        }
    }
    __syncthreads();

    const int kA = tid & 63;
    const int qg = tid >> 6;        // wave id == q-group (wave-uniform)
    const int qb = qg * 16;

    float sA[16], sB[16];
#pragma unroll
    for (int j = 0; j < 16; ++j) { sA[j] = 0.f; sB[j] = 0.f; }

    const float* KsA = &Ks[kA * 68];
    const float* KsB = &Ks[(kA + 64) * 68];

#pragma unroll 1
    for (int d0 = 0; d0 < 16; ++d0) {
        const float4 ka = *reinterpret_cast<const float4*>(KsA + d0 * 4);
        const float4 kb = *reinterpret_cast<const float4*>(KsB + d0 * 4);
#pragma unroll
        for (int j = 0; j < 16; ++j) {              // static j -> regs
            const float4 qv = *reinterpret_cast<const float4*>(&Qs[(qb + j) * ND + d0 * 4]);
            sA[j] = fmaf(ka.x, qv.x, fmaf(ka.y, qv.y, fmaf(ka.z, qv.z, fmaf(ka.w, qv.w, sA[j]))));
            sB[j] = fmaf(kb.x, qv.x, fmaf(kb.y, qv.y, fmaf(kb.z, qv.z, fmaf(kb.w, qv.w, sB[j]))));
        }
    }

    // column max over all 64 q: local over 16, then 4-way cross-wave via LDS
    float mA = sA[0], mB = sB[0];
#pragma unroll
    for (int j = 1; j < 16; ++j) { mA = fmaxf(mA, sA[j]); mB = fmaxf(mB, sB[j]); }
    Mloc[qg][kA] = mA; Mloc[qg][kA + 64] = mB;
    __syncthreads();
    mA = fmaxf(fmaxf(Mloc[0][kA], Mloc[1][kA]), fmaxf(Mloc[2][kA], Mloc[3][kA]));
    mB = fmaxf(fmaxf(Mloc[0][kA + 64], Mloc[1][kA + 64]),
               fmaxf(Mloc[2][kA + 64], Mloc[3][kA + 64]));

    float zA = 0.f, zB = 0.f;
#pragma unroll
    for (int j = 0; j < 16; ++j) {
        sA[j] = __expf((sA[j] - mA) * 0.125f); zA += sA[j];   // 1/sqrt(64) folded
        sB[j] = __expf((sB[j] - mB) * 0.125f); zB += sB[j];
    }
    Sloc[qg][kA] = zA; Sloc[qg][kA + 64] = zB;
    __syncthreads();
    zA = (Sloc[0][kA] + Sloc[1][kA]) + (Sloc[2][kA] + Sloc[3][kA]);
    zB = (Sloc[0][kA + 64] + Sloc[1][kA + 64]) + (Sloc[2][kA + 64] + Sloc[3][kA + 64]);
    const float invA = 1.f / zA;
    const float invB = 1.f / zB;

    float* __restrict__ arow = attn + ((size_t)b * NQ + qb) * NK + k0 + kA;
#pragma unroll
    for (int j = 0; j < 16; ++j) {
        const float pA = sA[j] * invA;
        const float pB = sB[j] * invB;
        arow[(size_t)j * NK]      = pA;     // lanes = consecutive k: coalesced
        arow[(size_t)j * NK + 64] = pB;
        float v = pA + pB;
#pragma unroll
        for (int off = 32; off > 0; off >>= 1) v += __shfl_xor(v, off, 64);
        if (kA == 0) atomicAdd(&rowsum[b * NQ + qb + j], v);
    }
}

// ---------------------------------------------------------------------------
// Kernel 2: per (b, 512-key tile).
//   - load attn tile (float4), scale by 1/(rowsum+eps), write back (final)
//   - out[b,q,:] += p_hat @ V via LDS tiles, atomicAdd into zeroed out.
// ---------------------------------------------------------------------------
#define KT 512
__global__ __launch_bounds__(256) void k_scale_pv(
    const float* __restrict__ value,
    const float* __restrict__ rowsum,
    float* __restrict__ attn,
    float* __restrict__ out)
{
    __shared__ alignas(16) float Ps[64][68];   // pad 68 keeps float4 rows aligned
    __shared__ alignas(16) float Vs[64][64];
    __shared__ float invs[NQ];

    const int b  = blockIdx.y;
    const int k0 = blockIdx.x * KT;
    const int tid = threadIdx.x;

    if (tid < NQ) invs[tid] = 1.f / (rowsum[b * NQ + tid] + 1e-8f);
    __syncthreads();

    const int tq = tid >> 4;   // q group of 4
    const int td = tid & 15;   // d group of 4

    float4 acc[4];
#pragma unroll
    for (int i = 0; i < 4; ++i) acc[i] = make_float4(0.f, 0.f, 0.f, 0.f);

    const int kk = tid & 63;
    const int r4 = tid >> 6;

    for (int kc = 0; kc < KT; kc += 64) {
        // stage + scale + writeback attn chunk, float4 (1024 float4 / 256 thr)
#pragma unroll
        for (int i = 0; i < 4; ++i) {
            const int idx = tid + 256 * i;
            const int q  = idx >> 4;
            const int c4 = (idx & 15) * 4;
            const size_t gi = ((size_t)(b * NQ + q)) * NK + (size_t)(k0 + kc + c4);
            float4 p = *reinterpret_cast<const float4*>(&attn[gi]);
            const float iv = invs[q];
            p.x *= iv; p.y *= iv; p.z *= iv; p.w *= iv;
            *reinterpret_cast<float4*>(&attn[gi]) = p;
            *reinterpret_cast<float4*>(&Ps[q][c4]) = p;
        }
        // stage value chunk (coalesced)
#pragma unroll
        for (int kk2 = 0; kk2 < 64; kk2 += 4) {
            const int krow = kk2 + r4;
            Vs[krow][kk] = value[((size_t)b * NK + (size_t)(k0 + kc + krow)) * ND + kk];
        }
        __syncthreads();

#pragma unroll 1
        for (int k1 = 0; k1 < 64; ++k1) {
            const float4 vv = *reinterpret_cast<const float4*>(&Vs[k1][td * 4]);
#pragma unroll
            for (int qi = 0; qi < 4; ++qi) {
                const float pq = Ps[tq * 4 + qi][k1];
                acc[qi].x = fmaf(pq, vv.x, acc[qi].x);
                acc[qi].y = fmaf(pq, vv.y, acc[qi].y);
                acc[qi].z = fmaf(pq, vv.z, acc[qi].z);
                acc[qi].w = fmaf(pq, vv.w, acc[qi].w);
            }
        }
        __syncthreads();
    }

#pragma unroll
    for (int qi = 0; qi < 4; ++qi) {
        float* op = out + ((size_t)(b * NQ + tq * 4 + qi)) * ND + td * 4;
        atomicAdd(op + 0, acc[qi].x);
        atomicAdd(op + 1, acc[qi].y);
        atomicAdd(op + 2, acc[qi].z);
        atomicAdd(op + 3, acc[qi].w);
    }
}

extern "C" void kernel_launch(void* const* d_in, const int* in_sizes, int n_in,
                              void* d_out, int out_size, void* d_ws, size_t ws_size,
                              hipStream_t stream) {
    const float* query = (const float*)d_in[0];
    const float* key   = (const float*)d_in[1];
    const float* value = (const float*)d_in[2];

    float* out  = (float*)d_out;                        // [B,Q,D]
    float* attn = (float*)d_out + (size_t)NB * NQ * ND; // [B,Q,K]
    float* rowsum = (float*)d_ws;                       // [B,Q]

    hipMemsetAsync(rowsum, 0, (size_t)NB * NQ * sizeof(float), stream);
    hipMemsetAsync(out, 0, (size_t)NB * NQ * ND * sizeof(float), stream);

    dim3 g1(NK / KPB, NB);
    k_qk_softmax<<<g1, 256, 0, stream>>>(query, key, attn, rowsum);

    dim3 g2(NK / KT, NB);
    k_scale_pv<<<g2, 256, 0, stream>>>(value, rowsum, attn, out);
}

// Round 4
// 210.668 us; speedup vs baseline: 1.4326x; 1.4326x over previous
//
#include <hip/hip_runtime.h>
#include <cstddef>

#define NB 64
#define NQ 64
#define NK 8192
#define ND 64
#define KPB 128

// ---------------------------------------------------------------------------
// Kernel 1: block = (b, 128-key tile), 256 threads (4 waves).
// Register-tiled QK^T: thread (tq=tid>>4, tk=tid&15) owns q = 4tq..+4 and
// k in {4tk..+4} U {64+4tk..+4}: 32 fp32 accumulators.
// Qt[d][q] and Kt[dd][k] staged TRANSPOSED in LDS with an XOR float4-group
// swizzle (group ^= (d>>2)&7): staging writes and compute reads are all
// <=2-way bank aliased (free). 3 ds_read_b128 -> 32 FMA per d-step.
// LDS = 16KB (Qt) + 16KB (Kt chunk, d in 2 chunks of 32) = 32KB -> 4-5 blk/CU.
// Softmax over q per key column: in-thread (4q) -> shfl over tq (xor 16,32)
// -> cross-wave via 4x128 LDS buffers aliased onto Kt.
// ---------------------------------------------------------------------------
__global__ __launch_bounds__(256, 4) void k_qk_softmax(
    const float* __restrict__ query,
    const float* __restrict__ key,
    float* __restrict__ attn,
    float* __restrict__ rowsum)
{
    __shared__ alignas(16) float Qt[64 * 64];    // [d][q swizzled] 16 KB
    __shared__ alignas(16) float Kt[32 * 128];   // [dd][k swizzled] 16 KB; M/S alias after

    const int tid = threadIdx.x;
    const int b   = blockIdx.y;
    const int k0  = blockIdx.x * KPB;
    const int tq  = tid >> 4;   // 0..15 -> q-quad 4tq
    const int tk  = tid & 15;   // 0..15 -> k-quads 4tk, 64+4tk

    // ---- stage Q transposed+swizzled: elem (d,q) at Qt[d*64 + ((q>>2 ^ s)<<2) + (q&3)], s=(d>>2)&7
    {
        const float4* qg = reinterpret_cast<const float4*>(query + (size_t)b * NQ * ND);
#pragma unroll
        for (int i = 0; i < 4; ++i) {
            const int idx = tid + 256 * i;      // 0..1023
            const int q   = idx >> 4;           // 0..63
            const int d4  = (idx & 15) * 4;     // 0..60
            float vv[4];
            *reinterpret_cast<float4*>(vv) = qg[idx];
#pragma unroll
            for (int j = 0; j < 4; ++j) {
                const int d = d4 + j;
                const int s = (d >> 2) & 7;
                Qt[d * 64 + ((((q >> 2) ^ s)) << 2) + (q & 3)] = vv[j];
            }
        }
    }

    float accA[4][4], accB[4][4];
#pragma unroll
    for (int qi = 0; qi < 4; ++qi)
#pragma unroll
        for (int e = 0; e < 4; ++e) { accA[qi][e] = 0.f; accB[qi][e] = 0.f; }

    const float4* kg = reinterpret_cast<const float4*>(key + ((size_t)b * NK + k0) * ND);

#pragma unroll 1
    for (int ch = 0; ch < 2; ++ch) {
        __syncthreads();   // Qt staged (ch=0) / previous chunk consumed (ch=1)
        // stage K chunk transposed+swizzled: rows d = ch*32 .. +32
#pragma unroll
        for (int i = 0; i < 4; ++i) {
            const int idx = tid + 256 * i;      // 0..1023
            const int k   = idx >> 3;           // 0..127
            const int d8  = idx & 7;            // float4 within half-row
            float vv[4];
            *reinterpret_cast<float4*>(vv) = kg[k * 16 + ch * 8 + d8];
#pragma unroll
            for (int j = 0; j < 4; ++j) {
                const int dd = d8 * 4 + j;      // 0..31
                const int s  = d8;              // ((ch*32+dd)>>2)&7 == d8
                Kt[dd * 128 + (((k >> 2) ^ s) << 2) + (k & 3)] = vv[j];
            }
        }
        __syncthreads();

        const int dbase = ch * 32;
#pragma unroll
        for (int d4 = 0; d4 < 8; ++d4) {
            const int s = d4;                   // (global d>>2)&7 for this d-quad
            const float* qp = &Qt[(dbase + d4 * 4) * 64 + ((tq ^ s) << 2)];
            const float* kp = &Kt[(d4 * 4) * 128 + ((tk ^ s) << 2)];
#pragma unroll
            for (int j = 0; j < 4; ++j) {
                float qf[4], ka[4], kb[4];
                *reinterpret_cast<float4*>(qf) = *reinterpret_cast<const float4*>(qp + j * 64);
                *reinterpret_cast<float4*>(ka) = *reinterpret_cast<const float4*>(kp + j * 128);
                *reinterpret_cast<float4*>(kb) = *reinterpret_cast<const float4*>(kp + j * 128 + 64);
#pragma unroll
                for (int qi = 0; qi < 4; ++qi) {
#pragma unroll
                    for (int e = 0; e < 4; ++e) {
                        accA[qi][e] = fmaf(qf[qi], ka[e], accA[qi][e]);
                        accB[qi][e] = fmaf(qf[qi], kb[e], accB[qi][e]);
                    }
                }
            }
        }
    }

    // ---- column max over all 64 q
    float mA[4], mB[4];
#pragma unroll
    for (int e = 0; e < 4; ++e) {
        mA[e] = fmaxf(fmaxf(accA[0][e], accA[1][e]), fmaxf(accA[2][e], accA[3][e]));
        mB[e] = fmaxf(fmaxf(accB[0][e], accB[1][e]), fmaxf(accB[2][e], accB[3][e]));
    }
#pragma unroll
    for (int e = 0; e < 4; ++e) {
        mA[e] = fmaxf(mA[e], __shfl_xor(mA[e], 16, 64));
        mA[e] = fmaxf(mA[e], __shfl_xor(mA[e], 32, 64));
        mB[e] = fmaxf(mB[e], __shfl_xor(mB[e], 16, 64));
        mB[e] = fmaxf(mB[e], __shfl_xor(mB[e], 32, 64));
    }

    float* Mred = Kt;          // [4][128] alias (Kt reads done)
    float* Sred = Kt + 512;    // [4][128]
    const int w = tid >> 6;

    __syncthreads();           // all waves done reading Kt
    if ((tid & 48) == 0) {
#pragma unroll
        for (int e = 0; e < 4; ++e) {
            Mred[w * 128 + 4 * tk + e]      = mA[e];
            Mred[w * 128 + 64 + 4 * tk + e] = mB[e];
        }
    }
    __syncthreads();
#pragma unroll
    for (int ww = 0; ww < 4; ++ww) {
        float ra[4], rb[4];
        *reinterpret_cast<float4*>(ra) = *reinterpret_cast<const float4*>(&Mred[ww * 128 + 4 * tk]);
        *reinterpret_cast<float4*>(rb) = *reinterpret_cast<const float4*>(&Mred[ww * 128 + 64 + 4 * tk]);
#pragma unroll
        for (int e = 0; e < 4; ++e) { mA[e] = fmaxf(mA[e], ra[e]); mB[e] = fmaxf(mB[e], rb[e]); }
    }

    // ---- exp((s - m)/8) and column sums
    float zA[4] = {0.f, 0.f, 0.f, 0.f}, zB[4] = {0.f, 0.f, 0.f, 0.f};
#pragma unroll
    for (int qi = 0; qi < 4; ++qi)
#pragma unroll
        for (int e = 0; e < 4; ++e) {
            accA[qi][e] = __expf((accA[qi][e] - mA[e]) * 0.125f); zA[e] += accA[qi][e];
            accB[qi][e] = __expf((accB[qi][e] - mB[e]) * 0.125f); zB[e] += accB[qi][e];
        }
#pragma unroll
    for (int e = 0; e < 4; ++e) {
        zA[e] += __shfl_xor(zA[e], 16, 64); zA[e] += __shfl_xor(zA[e], 32, 64);
        zB[e] += __shfl_xor(zB[e], 16, 64); zB[e] += __shfl_xor(zB[e], 32, 64);
    }
    if ((tid & 48) == 0) {
#pragma unroll
        for (int e = 0; e < 4; ++e) {
            Sred[w * 128 + 4 * tk + e]      = zA[e];
            Sred[w * 128 + 64 + 4 * tk + e] = zB[e];
        }
    }
    __syncthreads();
#pragma unroll
    for (int e = 0; e < 4; ++e) { zA[e] = 0.f; zB[e] = 0.f; }
#pragma unroll
    for (int ww = 0; ww < 4; ++ww) {
        float ra[4], rb[4];
        *reinterpret_cast<float4*>(ra) = *reinterpret_cast<const float4*>(&Sred[ww * 128 + 4 * tk]);
        *reinterpret_cast<float4*>(rb) = *reinterpret_cast<const float4*>(&Sred[ww * 128 + 64 + 4 * tk]);
#pragma unroll
        for (int e = 0; e < 4; ++e) { zA[e] += ra[e]; zB[e] += rb[e]; }
    }

    float invA[4], invB[4];
#pragma unroll
    for (int e = 0; e < 4; ++e) { invA[e] = 1.f / zA[e]; invB[e] = 1.f / zB[e]; }

    // ---- scale, store p (unnormalized-over-k attn), accumulate rowsum
    float* ap = attn + ((size_t)(b * NQ + tq * 4)) * NK + k0 + 4 * tk;
#pragma unroll
    for (int qi = 0; qi < 4; ++qi) {
        float pA[4], pB[4];
        float rq = 0.f;
#pragma unroll
        for (int e = 0; e < 4; ++e) {
            pA[e] = accA[qi][e] * invA[e];
            pB[e] = accB[qi][e] * invB[e];
            rq += pA[e] + pB[e];
        }
        *reinterpret_cast<float4*>(ap + (size_t)qi * NK)      = *reinterpret_cast<float4*>(pA);
        *reinterpret_cast<float4*>(ap + (size_t)qi * NK + 64) = *reinterpret_cast<float4*>(pB);
        rq += __shfl_xor(rq, 1, 64);
        rq += __shfl_xor(rq, 2, 64);
        rq += __shfl_xor(rq, 4, 64);
        rq += __shfl_xor(rq, 8, 64);
        if (tk == 0) atomicAdd(&rowsum[b * NQ + tq * 4 + qi], rq);
    }
}

// ---------------------------------------------------------------------------
// Kernel 2: per (b, 512-key tile).
//   - load attn tile (float4), scale by 1/(rowsum+eps), write back (final)
//   - out[b,q,:] += p_hat @ V via LDS tiles, atomicAdd into zeroed out.
// ---------------------------------------------------------------------------
#define KT 512
__global__ __launch_bounds__(256) void k_scale_pv(
    const float* __restrict__ value,
    const float* __restrict__ rowsum,
    float* __restrict__ attn,
    float* __restrict__ out)
{
    __shared__ alignas(16) float Ps[64][68];
    __shared__ alignas(16) float Vs[64][64];
    __shared__ float invs[NQ];

    const int b  = blockIdx.y;
    const int k0 = blockIdx.x * KT;
    const int tid = threadIdx.x;

    if (tid < NQ) invs[tid] = 1.f / (rowsum[b * NQ + tid] + 1e-8f);
    __syncthreads();

    const int tq = tid >> 4;   // q group of 4
    const int td = tid & 15;   // d group of 4

    float4 acc[4];
#pragma unroll
    for (int i = 0; i < 4; ++i) acc[i] = make_float4(0.f, 0.f, 0.f, 0.f);

#pragma unroll 1
    for (int kc = 0; kc < KT; kc += 64) {
        // stage + scale + writeback attn chunk, float4
#pragma unroll
        for (int i = 0; i < 4; ++i) {
            const int idx = tid + 256 * i;
            const int q  = idx >> 4;
            const int c4 = (idx & 15) * 4;
            const size_t gi = ((size_t)(b * NQ + q)) * NK + (size_t)(k0 + kc + c4);
            float4 p = *reinterpret_cast<const float4*>(&attn[gi]);
            const float iv = invs[q];
            p.x *= iv; p.y *= iv; p.z *= iv; p.w *= iv;
            *reinterpret_cast<float4*>(&attn[gi]) = p;
            *reinterpret_cast<float4*>(&Ps[q][c4]) = p;
        }
        // stage value chunk, float4
#pragma unroll
        for (int i = 0; i < 4; ++i) {
            const int idx  = tid + 256 * i;
            const int krow = idx >> 4;
            const int c4   = (idx & 15) * 4;
            *reinterpret_cast<float4*>(&Vs[krow][c4]) =
                *reinterpret_cast<const float4*>(&value[((size_t)b * NK + (size_t)(k0 + kc + krow)) * ND + c4]);
        }
        __syncthreads();

#pragma unroll 1
        for (int k1 = 0; k1 < 64; ++k1) {
            const float4 vv = *reinterpret_cast<const float4*>(&Vs[k1][td * 4]);
#pragma unroll
            for (int qi = 0; qi < 4; ++qi) {
                const float pq = Ps[tq * 4 + qi][k1];
                acc[qi].x = fmaf(pq, vv.x, acc[qi].x);
                acc[qi].y = fmaf(pq, vv.y, acc[qi].y);
                acc[qi].z = fmaf(pq, vv.z, acc[qi].z);
                acc[qi].w = fmaf(pq, vv.w, acc[qi].w);
            }
        }
        __syncthreads();
    }

#pragma unroll
    for (int qi = 0; qi < 4; ++qi) {
        float* op = out + ((size_t)(b * NQ + tq * 4 + qi)) * ND + td * 4;
        atomicAdd(op + 0, acc[qi].x);
        atomicAdd(op + 1, acc[qi].y);
        atomicAdd(op + 2, acc[qi].z);
        atomicAdd(op + 3, acc[qi].w);
    }
}

extern "C" void kernel_launch(void* const* d_in, const int* in_sizes, int n_in,
                              void* d_out, int out_size, void* d_ws, size_t ws_size,
                              hipStream_t stream) {
    const float* query = (const float*)d_in[0];
    const float* key   = (const float*)d_in[1];
    const float* value = (const float*)d_in[2];

    float* out  = (float*)d_out;                        // [B,Q,D]
    float* attn = (float*)d_out + (size_t)NB * NQ * ND; // [B,Q,K]
    float* rowsum = (float*)d_ws;                       // [B,Q]

    hipMemsetAsync(rowsum, 0, (size_t)NB * NQ * sizeof(float), stream);
    hipMemsetAsync(out, 0, (size_t)NB * NQ * ND * sizeof(float), stream);

    dim3 g1(NK / KPB, NB);
    k_qk_softmax<<<g1, 256, 0, stream>>>(query, key, attn, rowsum);

    dim3 g2(NK / KT, NB);
    k_scale_pv<<<g2, 256, 0, stream>>>(value, rowsum, attn, out);
}